// Round 4
// baseline (215.225 us; speedup 1.0000x reference)
//
#include <hip/hip_runtime.h>

#define BN_EPS 1e-5f

constexpr int PN0 = 262144, PN1 = 65536, PN2 = 16384, PN3 = 4096;

typedef __attribute__((ext_vector_type(8))) short short8;
typedef __attribute__((ext_vector_type(4))) float f32x4;

typedef const __attribute__((address_space(1))) unsigned int gu32;
typedef __attribute__((address_space(3))) unsigned int lu32;

__device__ __forceinline__ unsigned f2bf(float f) {
    unsigned u = __builtin_bit_cast(unsigned, f);
    u += 0x7fff + ((u >> 16) & 1);
    return u >> 16;
}
__device__ __forceinline__ float bf2f(unsigned h) {
    return __builtin_bit_cast(float, h << 16);
}

// ---------------- fused histogram of all three gather-index arrays ----------------
__global__ __launch_bounds__(256) void hist_all(const int* __restrict__ idx0,
                                                const int* __restrict__ idx1,
                                                const int* __restrict__ idx2,
                                                int* __restrict__ cnt3,
                                                int* __restrict__ cnt2,
                                                int* __restrict__ cnt1) {
    int i = blockIdx.x * 256 + threadIdx.x;
    if (blockIdx.y == 0) {
        if (i < PN2) atomicAdd(&cnt3[idx0[i]], 1);
    } else if (blockIdx.y == 1) {
        if (i < PN1) atomicAdd(&cnt2[idx1[i]], 1);
    } else {
        atomicAdd(&cnt1[idx2[i]], 1);
    }
}

// ---------------- weighted per-channel stats -> per-block partials ----------------
// src [R][C]; weight = cnt[r]. Optionally converts f32 src to bf16 (cvt_out).
template<int C, bool BF16SRC, bool CVT>
__global__ __launch_bounds__(256) void stats_k(const void* __restrict__ srcv,
                                               const int* __restrict__ cnt,
                                               float* __restrict__ part,
                                               unsigned short* __restrict__ cvt_out) {
    constexpr int G = C / 8;        // channel groups of 8
    constexpr int NL = 256 / G;     // row lanes
    __shared__ float red[NL][G][8];
    const int tid = threadIdx.x;
    const int cg = tid % G;
    const int lr = tid / G;
    const int r0 = blockIdx.x * (NL * 4);
    const float* srcf = (const float*)srcv;
    const unsigned short* srcb = (const unsigned short*)srcv;
    float s[8] = {}, q[8] = {};
    #pragma unroll
    for (int i = 0; i < 4; ++i) {
        int r = r0 + lr + NL * i;
        float w = (float)cnt[r];
        float v[8];
        if constexpr (BF16SRC) {
            uint4 u = *reinterpret_cast<const uint4*>(srcb + (size_t)r * C + cg * 8);
            unsigned uu[4] = {u.x, u.y, u.z, u.w};
            #pragma unroll
            for (int j = 0; j < 4; ++j) {
                v[2 * j]     = bf2f(uu[j] & 0xffffu);
                v[2 * j + 1] = bf2f(uu[j] >> 16);
            }
        } else {
            const float* p = srcf + (size_t)r * C + cg * 8;
            float4 a = *reinterpret_cast<const float4*>(p);
            float4 b = *reinterpret_cast<const float4*>(p + 4);
            v[0] = a.x; v[1] = a.y; v[2] = a.z; v[3] = a.w;
            v[4] = b.x; v[5] = b.y; v[6] = b.z; v[7] = b.w;
            if constexpr (CVT) {
                uint4 o;
                o.x = f2bf(v[0]) | (f2bf(v[1]) << 16);
                o.y = f2bf(v[2]) | (f2bf(v[3]) << 16);
                o.z = f2bf(v[4]) | (f2bf(v[5]) << 16);
                o.w = f2bf(v[6]) | (f2bf(v[7]) << 16);
                *reinterpret_cast<uint4*>(cvt_out + (size_t)r * C + cg * 8) = o;
            }
        }
        #pragma unroll
        for (int j = 0; j < 8; ++j) { s[j] += w * v[j]; q[j] += w * v[j] * v[j]; }
    }
    #pragma unroll
    for (int j = 0; j < 8; ++j) red[lr][cg][j] = s[j];
    __syncthreads();
    if (tid < G) {
        float ss[8] = {};
        #pragma unroll
        for (int l = 0; l < NL; ++l)
            #pragma unroll
            for (int j = 0; j < 8; ++j) ss[j] += red[l][tid][j];
        #pragma unroll
        for (int j = 0; j < 8; ++j)
            part[((size_t)blockIdx.x * C + tid * 8 + j) * 2] = ss[j];
    }
    __syncthreads();
    #pragma unroll
    for (int j = 0; j < 8; ++j) red[lr][cg][j] = q[j];
    __syncthreads();
    if (tid < G) {
        float qq[8] = {};
        #pragma unroll
        for (int l = 0; l < NL; ++l)
            #pragma unroll
            for (int j = 0; j < 8; ++j) qq[j] += red[l][tid][j];
        #pragma unroll
        for (int j = 0; j < 8; ++j)
            part[((size_t)blockIdx.x * C + tid * 8 + j) * 2 + 1] = qq[j];
    }
}

// ---------------- reduce partials -> scale/shift ----------------
__global__ __launch_bounds__(256) void redfin(const float* __restrict__ part, int NB, int C,
                                              const float* __restrict__ bnw,
                                              const float* __restrict__ bnb,
                                              float invN,
                                              float* __restrict__ scale,
                                              float* __restrict__ shift) {
    const int tid = threadIdx.x;
    const int c = blockIdx.x * 32 + (tid >> 3);
    const int j = tid & 7;
    float s = 0.f, q = 0.f;
    for (int b = j; b < NB; b += 8) {
        float2 p = *reinterpret_cast<const float2*>(part + ((size_t)b * C + c) * 2);
        s += p.x;
        q += p.y;
    }
    s += __shfl_xor(s, 1); s += __shfl_xor(s, 2); s += __shfl_xor(s, 4);
    q += __shfl_xor(q, 1); q += __shfl_xor(q, 2); q += __shfl_xor(q, 4);
    if (j == 0) {
        float mean = s * invN;
        float var = fmaxf(q * invN - mean * mean, 0.f);
        float sc = bnw[c] * rsqrtf(var + BN_EPS);
        scale[c] = sc;
        shift[c] = bnb[c] - mean * sc;
    }
}

// ---------------- prescale W -> pre-swizzled bf16 W' + d[n] ----------------
// Wp layout: [colblock=n/64][ (n64*K + k) ^ ((n64&7)<<3) ]   (ushort units)
template<int K>
__global__ __launch_bounds__(256) void prescale(const float* __restrict__ W,
                                                const float* __restrict__ scale,
                                                const float* __restrict__ shift,
                                                unsigned short* __restrict__ Wp,
                                                float* __restrict__ d) {
    const int tid = threadIdx.x;
    const int nl = tid >> 4;
    const int kc = tid & 15;
    const int n = blockIdx.x * 16 + nl;
    const int cb = n >> 6, n64 = n & 63;
    const float* wrow = W + (size_t)n * K;
    unsigned short* wp = Wp + (size_t)cb * 64 * K;
    float dp = 0.f;
    #pragma unroll
    for (int i = 0; i < K / 128; ++i) {
        int k = kc * 8 + i * 128;
        float4 w0 = *reinterpret_cast<const float4*>(wrow + k);
        float4 w1 = *reinterpret_cast<const float4*>(wrow + k + 4);
        float4 s0 = *reinterpret_cast<const float4*>(scale + k);
        float4 s1 = *reinterpret_cast<const float4*>(scale + k + 4);
        float4 h0 = *reinterpret_cast<const float4*>(shift + k);
        float4 h1 = *reinterpret_cast<const float4*>(shift + k + 4);
        dp += h0.x * w0.x + h0.y * w0.y + h0.z * w0.z + h0.w * w0.w
            + h1.x * w1.x + h1.y * w1.y + h1.z * w1.z + h1.w * w1.w;
        uint4 o;
        o.x = f2bf(w0.x * s0.x) | (f2bf(w0.y * s0.y) << 16);
        o.y = f2bf(w0.z * s0.z) | (f2bf(w0.w * s0.w) << 16);
        o.z = f2bf(w1.x * s1.x) | (f2bf(w1.y * s1.y) << 16);
        o.w = f2bf(w1.z * s1.z) | (f2bf(w1.w * s1.w) << 16);
        int si = (n64 * K + k) ^ ((n64 & 7) << 3);
        *reinterpret_cast<uint4*>(wp + si) = o;
    }
    dp += __shfl_xor(dp, 1); dp += __shfl_xor(dp, 2);
    dp += __shfl_xor(dp, 4); dp += __shfl_xor(dp, 8);
    if (kc == 0) d[n] = dp;
}

// ---------------- streaming gather-GEMM v2 ----------------
// out[m][n] = base[m][n] + sum_k x[idx[m]][k]*W'[n][k] + d[n]
// W' DMA'd (pre-swizzled bf16) to LDS; x gathered bf16; 4 waves, each wave
// processes 32-row pairs; mfma(W'frag, xfrag): lane -> row m=l15, cols lg*4+r.
template<int K, int MW, bool OUT_F32>
__global__ __launch_bounds__(256, MW) void gemm_v2(const unsigned short* __restrict__ src,
                                                   const int* __restrict__ idx,
                                                   const unsigned short* __restrict__ Wp,
                                                   const float* __restrict__ dvec,
                                                   const float* __restrict__ base,
                                                   void* __restrict__ outv,
                                                   int npairs, int C) {
    constexpr int KK = K / 32;
    constexpr int CH = (64 * K * 2) / 1024;  // 1KB DMA chunks
    __shared__ unsigned short Wl[64 * K];

    const int tid = threadIdx.x;
    const int lane = tid & 63;
    const int wv = tid >> 6;
    const int l15 = lane & 15, lg = lane >> 4;
    const int ncol0 = blockIdx.y * 64;

    // ---- async DMA W' tile into LDS (linear; source is pre-swizzled) ----
    {
        const char* g = (const char*)(Wp + (size_t)blockIdx.y * 64 * K);
        char* l = (char*)Wl;
        #pragma unroll
        for (int i = 0; i < CH / 4; ++i) {
            int ch = i * 4 + wv;
            __builtin_amdgcn_global_load_lds((gu32*)(g + ch * 1024 + lane * 16),
                                             (lu32*)(l + ch * 1024 + lane * 16), 16, 0, 0);
        }
    }

    float4 dr[4];
    #pragma unroll
    for (int ni = 0; ni < 4; ++ni)
        dr[ni] = *reinterpret_cast<const float4*>(&dvec[ncol0 + ni * 16 + lg * 4]);

    __syncthreads();  // barrier drains vmcnt -> DMA complete

    float* outf = (float*)outv;
    unsigned short* outb = (unsigned short*)outv;

    const int start = blockIdx.x * 4 + wv;
    const int step = gridDim.x * 4;

    int g0 = 0, g1 = 0;
    if (start < npairs) {
        g0 = idx[start * 32 + l15];
        g1 = idx[start * 32 + 16 + l15];
    }

    for (int p = start; p < npairs; p += step) {
        int pn = p + step;
        int h0 = 0, h1 = 0;
        if (pn < npairs) {
            h0 = idx[pn * 32 + l15];
            h1 = idx[pn * 32 + 16 + l15];
        }

        f32x4 acc0[4], acc1[4];
        #pragma unroll
        for (int ni = 0; ni < 4; ++ni) {
            acc0[ni] = (f32x4){0.f, 0.f, 0.f, 0.f};
            acc1[ni] = (f32x4){0.f, 0.f, 0.f, 0.f};
        }

        const unsigned short* x0 = src + (size_t)g0 * K + lg * 8;
        const unsigned short* x1 = src + (size_t)g1 * K + lg * 8;

        #pragma unroll 4
        for (int kk = 0; kk < KK; ++kk) {
            short8 xf0 = *reinterpret_cast<const short8*>(x0 + kk * 32);
            short8 xf1 = *reinterpret_cast<const short8*>(x1 + kk * 32);
            #pragma unroll
            for (int ni = 0; ni < 4; ++ni) {
                const int si = ((ni * 16 + l15) * K + kk * 32 + lg * 8) ^ ((l15 & 7) << 3);
                short8 wf = *reinterpret_cast<const short8*>(&Wl[si]);
                acc0[ni] = __builtin_amdgcn_mfma_f32_16x16x32_bf16(wf, xf0, acc0[ni], 0, 0, 0);
                acc1[ni] = __builtin_amdgcn_mfma_f32_16x16x32_bf16(wf, xf1, acc1[ni], 0, 0, 0);
            }
        }

        #pragma unroll
        for (int ni = 0; ni < 4; ++ni) {
            size_t off0 = (size_t)(p * 32 + l15) * C + ncol0 + ni * 16 + lg * 4;
            size_t off1 = off0 + (size_t)16 * C;
            float4 b0 = *reinterpret_cast<const float4*>(&base[off0]);
            float4 b1 = *reinterpret_cast<const float4*>(&base[off1]);
            float u0 = b0.x + dr[ni].x + acc0[ni][0];
            float u1 = b0.y + dr[ni].y + acc0[ni][1];
            float u2 = b0.z + dr[ni].z + acc0[ni][2];
            float u3 = b0.w + dr[ni].w + acc0[ni][3];
            float v0 = b1.x + dr[ni].x + acc1[ni][0];
            float v1 = b1.y + dr[ni].y + acc1[ni][1];
            float v2 = b1.z + dr[ni].z + acc1[ni][2];
            float v3 = b1.w + dr[ni].w + acc1[ni][3];
            if constexpr (OUT_F32) {
                *reinterpret_cast<float4*>(&outf[off0]) = make_float4(u0, u1, u2, u3);
                *reinterpret_cast<float4*>(&outf[off1]) = make_float4(v0, v1, v2, v3);
            } else {
                *reinterpret_cast<uint2*>(&outb[off0]) =
                    make_uint2(f2bf(u0) | (f2bf(u1) << 16), f2bf(u2) | (f2bf(u3) << 16));
                *reinterpret_cast<uint2*>(&outb[off1]) =
                    make_uint2(f2bf(v0) | (f2bf(v1) << 16), f2bf(v2) | (f2bf(v3) << 16));
            }
        }
        g0 = h0; g1 = h1;
    }
}

extern "C" void kernel_launch(void* const* d_in, const int* in_sizes, int n_in,
                              void* d_out, int out_size, void* d_ws, size_t ws_size,
                              hipStream_t stream) {
    const float* f0    = (const float*)d_in[0];
    const float* f1    = (const float*)d_in[1];
    const float* f2    = (const float*)d_in[2];
    const float* f3    = (const float*)d_in[3];
    const float* bn_w2 = (const float*)d_in[4];
    const float* bn_b2 = (const float*)d_in[5];
    const float* W2    = (const float*)d_in[6];
    const float* bn_w1 = (const float*)d_in[7];
    const float* bn_b1 = (const float*)d_in[8];
    const float* W1    = (const float*)d_in[9];
    const float* bn_w0 = (const float*)d_in[10];
    const float* bn_b0 = (const float*)d_in[11];
    const float* W0    = (const float*)d_in[12];
    const int*   idx0  = (const int*)d_in[13];
    const int*   idx1  = (const int*)d_in[14];
    const int*   idx2  = (const int*)d_in[15];
    float* out = (float*)d_out;

    // ---- workspace layout ----
    unsigned short* f3bf = (unsigned short*)d_ws;          // [PN3][512]  4MB
    unsigned short* f2p  = f3bf + (size_t)PN3 * 512;       // [PN2][256]  8MB
    unsigned short* f1p  = f2p + (size_t)PN2 * 256;        // [PN1][128] 16MB
    unsigned short* Wp2  = f1p + (size_t)PN1 * 128;        // [4][64][512]
    unsigned short* Wp1  = Wp2 + 4 * 64 * 512;             // [2][64][256]
    unsigned short* Wp0  = Wp1 + 2 * 64 * 256;             // [1][64][128]
    int* cnt3 = (int*)(Wp0 + 64 * 128);                    // zero region start
    int* cnt2 = cnt3 + PN3;
    int* cnt1 = cnt2 + PN2;                                // zero region end
    float* part2 = (float*)(cnt1 + PN1);                   // [256][512][2] 1MB
    float* part1 = part2 + 256 * 512 * 2;                  // [512][256][2] 1MB
    float* part0 = part1 + 512 * 256 * 2;                  // [1024][128][2] 1MB
    float* scale2 = part0 + 1024 * 128 * 2;
    float* shift2 = scale2 + 512;
    float* scale1 = shift2 + 512;
    float* shift1 = scale1 + 256;
    float* scale0 = shift1 + 256;
    float* shift0 = scale0 + 128;
    float* d2 = shift0 + 128;                              // 256
    float* d1 = d2 + 256;                                  // 128
    float* d0 = d1 + 128;                                  // 64

    hipMemsetAsync(cnt3, 0, (size_t)(PN3 + PN2 + PN1) * sizeof(int), stream);
    hist_all<<<dim3(PN0 / 256, 3), 256, 0, stream>>>(idx0, idx1, idx2, cnt3, cnt2, cnt1);

    // ---- level 2: f2p = f2 + BN(f3[idx0]) @ W2' ----
    stats_k<512, false, true><<<256, 256, 0, stream>>>(f3, cnt3, part2, f3bf);
    redfin<<<512 / 32, 256, 0, stream>>>(part2, 256, 512, bn_w2, bn_b2, 1.f / PN2, scale2, shift2);
    prescale<512><<<16, 256, 0, stream>>>(W2, scale2, shift2, Wp2, d2);
    gemm_v2<512, 2, false><<<dim3(128, 4), 256, 0, stream>>>(f3bf, idx0, Wp2, d2, f2, f2p,
                                                             PN2 / 32, 256);

    // ---- level 1: f1p = f1 + BN(f2p[idx1]) @ W1' ----
    stats_k<256, true, false><<<512, 256, 0, stream>>>(f2p, cnt2, part1, nullptr);
    redfin<<<256 / 32, 256, 0, stream>>>(part1, 512, 256, bn_w1, bn_b1, 1.f / PN1, scale1, shift1);
    prescale<256><<<8, 256, 0, stream>>>(W1, scale1, shift1, Wp1, d1);
    gemm_v2<256, 3, false><<<dim3(512, 2), 256, 0, stream>>>(f2p, idx1, Wp1, d1, f1, f1p,
                                                             PN1 / 32, 128);

    // ---- level 0: out = f0 + BN(f1p[idx2]) @ W0' ----
    stats_k<128, true, false><<<1024, 256, 0, stream>>>(f1p, cnt1, part0, nullptr);
    redfin<<<128 / 32, 256, 0, stream>>>(part0, 1024, 128, bn_w0, bn_b0, 1.f / PN0, scale0, shift0);
    prescale<128><<<4, 256, 0, stream>>>(W0, scale0, shift0, Wp0, d0);
    gemm_v2<128, 4, true><<<dim3(1024, 1), 256, 0, stream>>>(f1p, idx2, Wp0, d0, f0, out,
                                                             PN0 / 32, 64);
}

// Round 5
// 185.671 us; speedup vs baseline: 1.1592x; 1.1592x over previous
//
#include <hip/hip_runtime.h>

#define BN_EPS 1e-5f

constexpr int PN0 = 262144, PN1 = 65536, PN2 = 16384, PN3 = 4096;

typedef __attribute__((ext_vector_type(8))) short short8;
typedef __attribute__((ext_vector_type(4))) float f32x4;

typedef const __attribute__((address_space(1))) unsigned int gu32;
typedef __attribute__((address_space(3))) unsigned int lu32;

__device__ __forceinline__ unsigned f2bf(float f) {
    unsigned u = __builtin_bit_cast(unsigned, f);
    u += 0x7fff + ((u >> 16) & 1);
    return u >> 16;
}
__device__ __forceinline__ float bf2f(unsigned h) {
    return __builtin_bit_cast(float, h << 16);
}

// ---------------- fused histogram of all three gather-index arrays ----------------
__global__ __launch_bounds__(256) void hist_all(const int* __restrict__ idx0,
                                                const int* __restrict__ idx1,
                                                const int* __restrict__ idx2,
                                                int* __restrict__ cnt3,
                                                int* __restrict__ cnt2,
                                                int* __restrict__ cnt1) {
    int i = blockIdx.x * 256 + threadIdx.x;
    if (blockIdx.y == 0) {
        if (i < PN2) atomicAdd(&cnt3[idx0[i]], 1);
    } else if (blockIdx.y == 1) {
        if (i < PN1) atomicAdd(&cnt2[idx1[i]], 1);
    } else {
        atomicAdd(&cnt1[idx2[i]], 1);
    }
}

// ---------------- weighted per-channel stats -> per-block partials ----------------
template<int C, bool BF16SRC, bool CVT>
__global__ __launch_bounds__(256) void stats_k(const void* __restrict__ srcv,
                                               const int* __restrict__ cnt,
                                               float* __restrict__ part,
                                               unsigned short* __restrict__ cvt_out) {
    constexpr int G = C / 8;
    constexpr int NL = 256 / G;
    __shared__ float red[NL][G][8];
    const int tid = threadIdx.x;
    const int cg = tid % G;
    const int lr = tid / G;
    const int r0 = blockIdx.x * (NL * 4);
    const float* srcf = (const float*)srcv;
    const unsigned short* srcb = (const unsigned short*)srcv;
    float s[8] = {}, q[8] = {};
    #pragma unroll
    for (int i = 0; i < 4; ++i) {
        int r = r0 + lr + NL * i;
        float w = (float)cnt[r];
        float v[8];
        if constexpr (BF16SRC) {
            uint4 u = *reinterpret_cast<const uint4*>(srcb + (size_t)r * C + cg * 8);
            unsigned uu[4] = {u.x, u.y, u.z, u.w};
            #pragma unroll
            for (int j = 0; j < 4; ++j) {
                v[2 * j]     = bf2f(uu[j] & 0xffffu);
                v[2 * j + 1] = bf2f(uu[j] >> 16);
            }
        } else {
            const float* p = srcf + (size_t)r * C + cg * 8;
            float4 a = *reinterpret_cast<const float4*>(p);
            float4 b = *reinterpret_cast<const float4*>(p + 4);
            v[0] = a.x; v[1] = a.y; v[2] = a.z; v[3] = a.w;
            v[4] = b.x; v[5] = b.y; v[6] = b.z; v[7] = b.w;
            if constexpr (CVT) {
                uint4 o;
                o.x = f2bf(v[0]) | (f2bf(v[1]) << 16);
                o.y = f2bf(v[2]) | (f2bf(v[3]) << 16);
                o.z = f2bf(v[4]) | (f2bf(v[5]) << 16);
                o.w = f2bf(v[6]) | (f2bf(v[7]) << 16);
                *reinterpret_cast<uint4*>(cvt_out + (size_t)r * C + cg * 8) = o;
            }
        }
        #pragma unroll
        for (int j = 0; j < 8; ++j) { s[j] += w * v[j]; q[j] += w * v[j] * v[j]; }
    }
    #pragma unroll
    for (int j = 0; j < 8; ++j) red[lr][cg][j] = s[j];
    __syncthreads();
    if (tid < G) {
        float ss[8] = {};
        #pragma unroll
        for (int l = 0; l < NL; ++l)
            #pragma unroll
            for (int j = 0; j < 8; ++j) ss[j] += red[l][tid][j];
        #pragma unroll
        for (int j = 0; j < 8; ++j)
            part[((size_t)blockIdx.x * C + tid * 8 + j) * 2] = ss[j];
    }
    __syncthreads();
    #pragma unroll
    for (int j = 0; j < 8; ++j) red[lr][cg][j] = q[j];
    __syncthreads();
    if (tid < G) {
        float qq[8] = {};
        #pragma unroll
        for (int l = 0; l < NL; ++l)
            #pragma unroll
            for (int j = 0; j < 8; ++j) qq[j] += red[l][tid][j];
        #pragma unroll
        for (int j = 0; j < 8; ++j)
            part[((size_t)blockIdx.x * C + tid * 8 + j) * 2 + 1] = qq[j];
    }
}

// ---------------- reduce partials -> scale/shift ----------------
__global__ __launch_bounds__(256) void redfin(const float* __restrict__ part, int NB, int C,
                                              const float* __restrict__ bnw,
                                              const float* __restrict__ bnb,
                                              float invN,
                                              float* __restrict__ scale,
                                              float* __restrict__ shift) {
    const int tid = threadIdx.x;
    const int c = blockIdx.x * 32 + (tid >> 3);
    const int j = tid & 7;
    float s = 0.f, q = 0.f;
    for (int b = j; b < NB; b += 8) {
        float2 p = *reinterpret_cast<const float2*>(part + ((size_t)b * C + c) * 2);
        s += p.x;
        q += p.y;
    }
    s += __shfl_xor(s, 1); s += __shfl_xor(s, 2); s += __shfl_xor(s, 4);
    q += __shfl_xor(q, 1); q += __shfl_xor(q, 2); q += __shfl_xor(q, 4);
    if (j == 0) {
        float mean = s * invN;
        float var = fmaxf(q * invN - mean * mean, 0.f);
        float sc = bnw[c] * rsqrtf(var + BN_EPS);
        scale[c] = sc;
        shift[c] = bnb[c] - mean * sc;
    }
}

// ---------------- prescale W -> pre-swizzled bf16 W' + d[n] ----------------
template<int K>
__global__ __launch_bounds__(256) void prescale(const float* __restrict__ W,
                                                const float* __restrict__ scale,
                                                const float* __restrict__ shift,
                                                unsigned short* __restrict__ Wp,
                                                float* __restrict__ d) {
    const int tid = threadIdx.x;
    const int nl = tid >> 4;
    const int kc = tid & 15;
    const int n = blockIdx.x * 16 + nl;
    const int cb = n >> 6, n64 = n & 63;
    const float* wrow = W + (size_t)n * K;
    unsigned short* wp = Wp + (size_t)cb * 64 * K;
    float dp = 0.f;
    #pragma unroll
    for (int i = 0; i < K / 128; ++i) {
        int k = kc * 8 + i * 128;
        float4 w0 = *reinterpret_cast<const float4*>(wrow + k);
        float4 w1 = *reinterpret_cast<const float4*>(wrow + k + 4);
        float4 s0 = *reinterpret_cast<const float4*>(scale + k);
        float4 s1 = *reinterpret_cast<const float4*>(scale + k + 4);
        float4 h0 = *reinterpret_cast<const float4*>(shift + k);
        float4 h1 = *reinterpret_cast<const float4*>(shift + k + 4);
        dp += h0.x * w0.x + h0.y * w0.y + h0.z * w0.z + h0.w * w0.w
            + h1.x * w1.x + h1.y * w1.y + h1.z * w1.z + h1.w * w1.w;
        uint4 o;
        o.x = f2bf(w0.x * s0.x) | (f2bf(w0.y * s0.y) << 16);
        o.y = f2bf(w0.z * s0.z) | (f2bf(w0.w * s0.w) << 16);
        o.z = f2bf(w1.x * s1.x) | (f2bf(w1.y * s1.y) << 16);
        o.w = f2bf(w1.z * s1.z) | (f2bf(w1.w * s1.w) << 16);
        int si = (n64 * K + k) ^ ((n64 & 7) << 3);
        *reinterpret_cast<uint4*>(wp + si) = o;
    }
    dp += __shfl_xor(dp, 1); dp += __shfl_xor(dp, 2);
    dp += __shfl_xor(dp, 4); dp += __shfl_xor(dp, 8);
    if (kc == 0) d[n] = dp;
}

// ---------------- one-shot gather-GEMM ----------------
// Each wave: one 16-row chunk x one 64-col panel. All global loads issued
// before the barrier (overlap W' DMA with own gathers); then ds_read+MFMA
// burst; then FMA+store epilogue. No loops, exact partition.
template<int K, int C, int WAVES, bool OUT_F32>
__global__ __launch_bounds__(WAVES * 64, WAVES == 8 ? 2 : 4)
void gemm_v3(const unsigned short* __restrict__ src,
             const int* __restrict__ idx,
             const unsigned short* __restrict__ Wp,
             const float* __restrict__ dvec,
             const float* __restrict__ base,
             void* __restrict__ outv) {
    constexpr int KK = K / 32;
    constexpr int CH = K / 8;  // 1KB DMA chunks of the 64*K*2-byte panel
    __shared__ unsigned short Wl[64 * K];

    const int tid = threadIdx.x;
    const int lane = tid & 63;
    const int wv = tid >> 6;
    const int l15 = lane & 15, lg = lane >> 4;
    const int ncol0 = blockIdx.y * 64;
    const int chunk = blockIdx.x * WAVES + wv;

    // ---- issue W' panel DMA (pre-swizzled source, linear dest) ----
    {
        const char* g = (const char*)(Wp + (size_t)blockIdx.y * 64 * K);
        char* l = (char*)Wl;
        #pragma unroll
        for (int i = 0; i < CH / WAVES; ++i) {
            int ch = i * WAVES + wv;
            __builtin_amdgcn_global_load_lds((gu32*)(g + ch * 1024 + lane * 16),
                                             (lu32*)(l + ch * 1024 + lane * 16), 16, 0, 0);
        }
    }

    // ---- issue all per-wave loads: idx -> x gather, base, d ----
    const int g0 = idx[chunk * 16 + l15];
    const unsigned short* xp = src + (size_t)g0 * K + lg * 8;
    short8 xf[KK];
    #pragma unroll
    for (int kk = 0; kk < KK; ++kk)
        xf[kk] = *reinterpret_cast<const short8*>(xp + kk * 32);

    const size_t rowoff = (size_t)(chunk * 16 + l15) * C + ncol0;
    float4 bs[4], dr[4];
    #pragma unroll
    for (int ni = 0; ni < 4; ++ni) {
        bs[ni] = *reinterpret_cast<const float4*>(&base[rowoff + ni * 16 + lg * 4]);
        dr[ni] = *reinterpret_cast<const float4*>(&dvec[ncol0 + ni * 16 + lg * 4]);
    }

    __syncthreads();  // per-wave vmcnt drain + DMA completion

    // ---- MFMA burst ----
    f32x4 acc[4];
    #pragma unroll
    for (int ni = 0; ni < 4; ++ni) acc[ni] = (f32x4){0.f, 0.f, 0.f, 0.f};
    #pragma unroll
    for (int kk = 0; kk < KK; ++kk) {
        #pragma unroll
        for (int ni = 0; ni < 4; ++ni) {
            const int si = ((ni * 16 + l15) * K + kk * 32 + lg * 8) ^ ((l15 & 7) << 3);
            short8 wf = *reinterpret_cast<const short8*>(&Wl[si]);
            acc[ni] = __builtin_amdgcn_mfma_f32_16x16x32_bf16(wf, xf[kk], acc[ni], 0, 0, 0);
        }
    }

    // ---- epilogue ----
    float* outf = (float*)outv;
    unsigned short* outb = (unsigned short*)outv;
    #pragma unroll
    for (int ni = 0; ni < 4; ++ni) {
        size_t off = rowoff + ni * 16 + lg * 4;
        float v0 = bs[ni].x + dr[ni].x + acc[ni][0];
        float v1 = bs[ni].y + dr[ni].y + acc[ni][1];
        float v2 = bs[ni].z + dr[ni].z + acc[ni][2];
        float v3 = bs[ni].w + dr[ni].w + acc[ni][3];
        if constexpr (OUT_F32) {
            *reinterpret_cast<float4*>(&outf[off]) = make_float4(v0, v1, v2, v3);
        } else {
            *reinterpret_cast<uint2*>(&outb[off]) =
                make_uint2(f2bf(v0) | (f2bf(v1) << 16), f2bf(v2) | (f2bf(v3) << 16));
        }
    }
}

extern "C" void kernel_launch(void* const* d_in, const int* in_sizes, int n_in,
                              void* d_out, int out_size, void* d_ws, size_t ws_size,
                              hipStream_t stream) {
    const float* f0    = (const float*)d_in[0];
    const float* f1    = (const float*)d_in[1];
    const float* f2    = (const float*)d_in[2];
    const float* f3    = (const float*)d_in[3];
    const float* bn_w2 = (const float*)d_in[4];
    const float* bn_b2 = (const float*)d_in[5];
    const float* W2    = (const float*)d_in[6];
    const float* bn_w1 = (const float*)d_in[7];
    const float* bn_b1 = (const float*)d_in[8];
    const float* W1    = (const float*)d_in[9];
    const float* bn_w0 = (const float*)d_in[10];
    const float* bn_b0 = (const float*)d_in[11];
    const float* W0    = (const float*)d_in[12];
    const int*   idx0  = (const int*)d_in[13];
    const int*   idx1  = (const int*)d_in[14];
    const int*   idx2  = (const int*)d_in[15];
    float* out = (float*)d_out;

    // ---- workspace layout ----
    unsigned short* f3bf = (unsigned short*)d_ws;          // [PN3][512]  4MB
    unsigned short* f2p  = f3bf + (size_t)PN3 * 512;       // [PN2][256]  8MB
    unsigned short* f1p  = f2p + (size_t)PN2 * 256;        // [PN1][128] 16MB
    unsigned short* Wp2  = f1p + (size_t)PN1 * 128;        // [4][64][512]
    unsigned short* Wp1  = Wp2 + 4 * 64 * 512;             // [2][64][256]
    unsigned short* Wp0  = Wp1 + 2 * 64 * 256;             // [1][64][128]
    int* cnt3 = (int*)(Wp0 + 64 * 128);                    // zero region start
    int* cnt2 = cnt3 + PN3;
    int* cnt1 = cnt2 + PN2;                                // zero region end
    float* part2 = (float*)(cnt1 + PN1);                   // [256][512][2] 1MB
    float* part1 = part2 + 256 * 512 * 2;                  // [512][256][2] 1MB
    float* part0 = part1 + 512 * 256 * 2;                  // [1024][128][2] 1MB
    float* scale2 = part0 + 1024 * 128 * 2;
    float* shift2 = scale2 + 512;
    float* scale1 = shift2 + 512;
    float* shift1 = scale1 + 256;
    float* scale0 = shift1 + 256;
    float* shift0 = scale0 + 128;
    float* d2 = shift0 + 128;                              // 256
    float* d1 = d2 + 256;                                  // 128
    float* d0 = d1 + 128;                                  // 64

    hipMemsetAsync(cnt3, 0, (size_t)(PN3 + PN2 + PN1) * sizeof(int), stream);
    hist_all<<<dim3(PN0 / 256, 3), 256, 0, stream>>>(idx0, idx1, idx2, cnt3, cnt2, cnt1);

    // ---- level 2: f2p = f2 + BN(f3[idx0]) @ W2' ----
    stats_k<512, false, true><<<256, 256, 0, stream>>>(f3, cnt3, part2, f3bf);
    redfin<<<512 / 32, 256, 0, stream>>>(part2, 256, 512, bn_w2, bn_b2, 1.f / PN2, scale2, shift2);
    prescale<512><<<16, 256, 0, stream>>>(W2, scale2, shift2, Wp2, d2);
    gemm_v3<512, 256, 8, false><<<dim3(PN2 / 16 / 8, 4), 512, 0, stream>>>(
        f3bf, idx0, Wp2, d2, f2, f2p);

    // ---- level 1: f1p = f1 + BN(f2p[idx1]) @ W1' ----
    stats_k<256, true, false><<<512, 256, 0, stream>>>(f2p, cnt2, part1, nullptr);
    redfin<<<256 / 32, 256, 0, stream>>>(part1, 512, 256, bn_w1, bn_b1, 1.f / PN1, scale1, shift1);
    prescale<256><<<8, 256, 0, stream>>>(W1, scale1, shift1, Wp1, d1);
    gemm_v3<256, 128, 4, false><<<dim3(PN1 / 16 / 4, 2), 256, 0, stream>>>(
        f2p, idx1, Wp1, d1, f1, f1p);

    // ---- level 0: out = f0 + BN(f1p[idx2]) @ W0' ----
    stats_k<128, true, false><<<1024, 256, 0, stream>>>(f1p, cnt1, part0, nullptr);
    redfin<<<128 / 32, 256, 0, stream>>>(part0, 1024, 128, bn_w0, bn_b0, 1.f / PN0, scale0, shift0);
    prescale<128><<<4, 256, 0, stream>>>(W0, scale0, shift0, Wp0, d0);
    gemm_v3<128, 64, 4, true><<<dim3(PN0 / 16 / 4, 1), 256, 0, stream>>>(
        f1p, idx2, Wp0, d0, f0, out);
}

// Round 6
// 175.079 us; speedup vs baseline: 1.2293x; 1.0605x over previous
//
#include <hip/hip_runtime.h>

#define BN_EPS 1e-5f

constexpr int PN0 = 262144, PN1 = 65536, PN2 = 16384, PN3 = 4096;
constexpr size_t MB = 1u << 20;

typedef __attribute__((ext_vector_type(8))) short short8;
typedef __attribute__((ext_vector_type(4))) float f32x4;

typedef const __attribute__((address_space(1))) unsigned int gu32;
typedef __attribute__((address_space(3))) unsigned int lu32;

__device__ __forceinline__ unsigned f2bf(float f) {
    unsigned u = __builtin_bit_cast(unsigned, f);
    u += 0x7fff + ((u >> 16) & 1);
    return u >> 16;
}
__device__ __forceinline__ float bf2f(unsigned h) {
    return __builtin_bit_cast(float, h << 16);
}

// ---------------- fused histogram of all three gather-index arrays ----------------
__global__ __launch_bounds__(256) void hist_all(const int* __restrict__ idx0,
                                                const int* __restrict__ idx1,
                                                const int* __restrict__ idx2,
                                                int* __restrict__ cnt3,
                                                int* __restrict__ cnt2,
                                                int* __restrict__ cnt1) {
    int i = blockIdx.x * 256 + threadIdx.x;
    if (blockIdx.y == 0) {
        if (i < PN2) atomicAdd(&cnt3[idx0[i]], 1);
    } else if (blockIdx.y == 1) {
        if (i < PN1) atomicAdd(&cnt2[idx1[i]], 1);
    } else {
        atomicAdd(&cnt1[idx2[i]], 1);
    }
}

// ---------------- weighted per-channel stats over f3 (+convert to bf16) ----------------
template<int C>
__global__ __launch_bounds__(256) void stats_f3(const float* __restrict__ src,
                                                const int* __restrict__ cnt,
                                                float* __restrict__ part,
                                                unsigned short* __restrict__ cvt_out) {
    constexpr int G = C / 8;
    constexpr int NL = 256 / G;
    __shared__ float red[NL][G][8];
    const int tid = threadIdx.x;
    const int cg = tid % G;
    const int lr = tid / G;
    const int r0 = blockIdx.x * (NL * 4);
    float s[8] = {}, q[8] = {};
    #pragma unroll
    for (int i = 0; i < 4; ++i) {
        int r = r0 + lr + NL * i;
        float w = (float)cnt[r];
        const float* p = src + (size_t)r * C + cg * 8;
        float4 a = *reinterpret_cast<const float4*>(p);
        float4 b = *reinterpret_cast<const float4*>(p + 4);
        float v[8] = {a.x, a.y, a.z, a.w, b.x, b.y, b.z, b.w};
        uint4 o;
        o.x = f2bf(v[0]) | (f2bf(v[1]) << 16);
        o.y = f2bf(v[2]) | (f2bf(v[3]) << 16);
        o.z = f2bf(v[4]) | (f2bf(v[5]) << 16);
        o.w = f2bf(v[6]) | (f2bf(v[7]) << 16);
        *reinterpret_cast<uint4*>(cvt_out + (size_t)r * C + cg * 8) = o;
        #pragma unroll
        for (int j = 0; j < 8; ++j) { s[j] += w * v[j]; q[j] += w * v[j] * v[j]; }
    }
    #pragma unroll
    for (int j = 0; j < 8; ++j) red[lr][cg][j] = s[j];
    __syncthreads();
    if (tid < G) {
        float ss[8] = {};
        #pragma unroll
        for (int l = 0; l < NL; ++l)
            #pragma unroll
            for (int j = 0; j < 8; ++j) ss[j] += red[l][tid][j];
        #pragma unroll
        for (int j = 0; j < 8; ++j)
            part[((size_t)blockIdx.x * C + tid * 8 + j) * 2] = ss[j];
    }
    __syncthreads();
    #pragma unroll
    for (int j = 0; j < 8; ++j) red[lr][cg][j] = q[j];
    __syncthreads();
    if (tid < G) {
        float qq[8] = {};
        #pragma unroll
        for (int l = 0; l < NL; ++l)
            #pragma unroll
            for (int j = 0; j < 8; ++j) qq[j] += red[l][tid][j];
        #pragma unroll
        for (int j = 0; j < 8; ++j)
            part[((size_t)blockIdx.x * C + tid * 8 + j) * 2 + 1] = qq[j];
    }
}

// ---------------- reduce partials -> scale/shift ----------------
__global__ __launch_bounds__(256) void redfin(const float* __restrict__ part, int NB, int C,
                                              const float* __restrict__ bnw,
                                              const float* __restrict__ bnb,
                                              float invN,
                                              float* __restrict__ scale,
                                              float* __restrict__ shift) {
    const int tid = threadIdx.x;
    const int c = blockIdx.x * 32 + (tid >> 3);
    const int j = tid & 7;
    float s = 0.f, q = 0.f;
    for (int b = j; b < NB; b += 8) {
        float2 p = *reinterpret_cast<const float2*>(part + ((size_t)b * C + c) * 2);
        s += p.x;
        q += p.y;
    }
    s += __shfl_xor(s, 1); s += __shfl_xor(s, 2); s += __shfl_xor(s, 4);
    q += __shfl_xor(q, 1); q += __shfl_xor(q, 2); q += __shfl_xor(q, 4);
    if (j == 0) {
        float mean = s * invN;
        float var = fmaxf(q * invN - mean * mean, 0.f);
        float sc = bnw[c] * rsqrtf(var + BN_EPS);
        scale[c] = sc;
        shift[c] = bnb[c] - mean * sc;
    }
}

// ---------------- prescale W -> pre-swizzled bf16 W' + d[n] ----------------
template<int K>
__global__ __launch_bounds__(256) void prescale(const float* __restrict__ W,
                                                const float* __restrict__ scale,
                                                const float* __restrict__ shift,
                                                unsigned short* __restrict__ Wp,
                                                float* __restrict__ d) {
    const int tid = threadIdx.x;
    const int nl = tid >> 4;
    const int kc = tid & 15;
    const int n = blockIdx.x * 16 + nl;
    const int cb = n >> 6, n64 = n & 63;
    const float* wrow = W + (size_t)n * K;
    unsigned short* wp = Wp + (size_t)cb * 64 * K;
    float dp = 0.f;
    #pragma unroll
    for (int i = 0; i < K / 128; ++i) {
        int k = kc * 8 + i * 128;
        float4 w0 = *reinterpret_cast<const float4*>(wrow + k);
        float4 w1 = *reinterpret_cast<const float4*>(wrow + k + 4);
        float4 s0 = *reinterpret_cast<const float4*>(scale + k);
        float4 s1 = *reinterpret_cast<const float4*>(scale + k + 4);
        float4 h0 = *reinterpret_cast<const float4*>(shift + k);
        float4 h1 = *reinterpret_cast<const float4*>(shift + k + 4);
        dp += h0.x * w0.x + h0.y * w0.y + h0.z * w0.z + h0.w * w0.w
            + h1.x * w1.x + h1.y * w1.y + h1.z * w1.z + h1.w * w1.w;
        uint4 o;
        o.x = f2bf(w0.x * s0.x) | (f2bf(w0.y * s0.y) << 16);
        o.y = f2bf(w0.z * s0.z) | (f2bf(w0.w * s0.w) << 16);
        o.z = f2bf(w1.x * s1.x) | (f2bf(w1.y * s1.y) << 16);
        o.w = f2bf(w1.z * s1.z) | (f2bf(w1.w * s1.w) << 16);
        int si = (n64 * K + k) ^ ((n64 & 7) << 3);
        *reinterpret_cast<uint4*>(wp + si) = o;
    }
    dp += __shfl_xor(dp, 1); dp += __shfl_xor(dp, 2);
    dp += __shfl_xor(dp, 4); dp += __shfl_xor(dp, 8);
    if (kc == 0) d[n] = dp;
}

// ---------------- dense one-shot GEMM over the coarse level ----------------
// dec[m][n] = sum_k x[m][k]*W'[n][k] + d[n]; rows linear (no gather).
template<int K, int C, int WAVES>
__global__ __launch_bounds__(WAVES * 64, 4)
void gemm_dense(const unsigned short* __restrict__ src,
                const unsigned short* __restrict__ Wp,
                const float* __restrict__ dvec,
                unsigned short* __restrict__ dec) {
    constexpr int KK = K / 32;
    constexpr int CH = K / 8;  // 1KB DMA chunks of the 64*K*2-byte panel
    __shared__ unsigned short Wl[64 * K];

    const int tid = threadIdx.x;
    const int lane = tid & 63;
    const int wv = tid >> 6;
    const int l15 = lane & 15, lg = lane >> 4;
    const int ncol0 = blockIdx.y * 64;
    const int chunk = blockIdx.x * WAVES + wv;

    {
        const char* g = (const char*)(Wp + (size_t)blockIdx.y * 64 * K);
        char* l = (char*)Wl;
        #pragma unroll
        for (int i = 0; i < CH / WAVES; ++i) {
            int ch = i * WAVES + wv;
            __builtin_amdgcn_global_load_lds((gu32*)(g + ch * 1024 + lane * 16),
                                             (lu32*)(l + ch * 1024 + lane * 16), 16, 0, 0);
        }
    }

    const unsigned short* xp = src + (size_t)(chunk * 16 + l15) * K + lg * 8;
    short8 xf[KK];
    #pragma unroll
    for (int kk = 0; kk < KK; ++kk)
        xf[kk] = *reinterpret_cast<const short8*>(xp + kk * 32);

    float4 dr[4];
    #pragma unroll
    for (int ni = 0; ni < 4; ++ni)
        dr[ni] = *reinterpret_cast<const float4*>(&dvec[ncol0 + ni * 16 + lg * 4]);

    __syncthreads();

    f32x4 acc[4];
    #pragma unroll
    for (int ni = 0; ni < 4; ++ni) acc[ni] = (f32x4){0.f, 0.f, 0.f, 0.f};
    #pragma unroll
    for (int kk = 0; kk < KK; ++kk) {
        #pragma unroll
        for (int ni = 0; ni < 4; ++ni) {
            const int si = ((ni * 16 + l15) * K + kk * 32 + lg * 8) ^ ((l15 & 7) << 3);
            short8 wf = *reinterpret_cast<const short8*>(&Wl[si]);
            acc[ni] = __builtin_amdgcn_mfma_f32_16x16x32_bf16(wf, xf[kk], acc[ni], 0, 0, 0);
        }
    }

    const size_t rowoff = (size_t)(chunk * 16 + l15) * C + ncol0;
    #pragma unroll
    for (int ni = 0; ni < 4; ++ni) {
        size_t off = rowoff + ni * 16 + lg * 4;
        float v0 = dr[ni].x + acc[ni][0];
        float v1 = dr[ni].y + acc[ni][1];
        float v2 = dr[ni].z + acc[ni][2];
        float v3 = dr[ni].w + acc[ni][3];
        *reinterpret_cast<uint2*>(&dec[off]) =
            make_uint2(f2bf(v0) | (f2bf(v1) << 16), f2bf(v2) | (f2bf(v3) << 16));
    }
}

// ---------------- streaming gather-add (+ optional fused weighted stats) ----------------
// out[r][c] = base[r][c] + dec[idx[r]][c]; stats: s[c]+=w_r*out, q[c]+=w_r*out^2.
template<int C, int IT, bool STATS, bool OUT_F32>
__global__ __launch_bounds__(256) void gather_add(const float* __restrict__ base,
                                                  const unsigned short* __restrict__ dec,
                                                  const int* __restrict__ idx,
                                                  const int* __restrict__ cnt_next,
                                                  void* __restrict__ outv,
                                                  float* __restrict__ part) {
    constexpr int G = C / 8;
    constexpr int NL = 256 / G;
    __shared__ float red[NL][G][8];
    const int tid = threadIdx.x;
    const int cg = tid % G;
    const int lr = tid / G;
    const int r0 = blockIdx.x * (NL * IT);
    float s[8] = {}, q[8] = {};
    #pragma unroll
    for (int i = 0; i < IT; ++i) {
        const int r = r0 + lr + NL * i;
        const int g = idx[r];
        uint4 u = *reinterpret_cast<const uint4*>(dec + (size_t)g * C + cg * 8);
        const float* bp = base + (size_t)r * C + cg * 8;
        float4 b0 = *reinterpret_cast<const float4*>(bp);
        float4 b1 = *reinterpret_cast<const float4*>(bp + 4);
        unsigned uu[4] = {u.x, u.y, u.z, u.w};
        float v[8];
        v[0] = b0.x + bf2f(uu[0] & 0xffffu); v[1] = b0.y + bf2f(uu[0] >> 16);
        v[2] = b0.z + bf2f(uu[1] & 0xffffu); v[3] = b0.w + bf2f(uu[1] >> 16);
        v[4] = b1.x + bf2f(uu[2] & 0xffffu); v[5] = b1.y + bf2f(uu[2] >> 16);
        v[6] = b1.z + bf2f(uu[3] & 0xffffu); v[7] = b1.w + bf2f(uu[3] >> 16);
        if constexpr (OUT_F32) {
            float* op = (float*)outv + (size_t)r * C + cg * 8;
            *reinterpret_cast<float4*>(op) = make_float4(v[0], v[1], v[2], v[3]);
            *reinterpret_cast<float4*>(op + 4) = make_float4(v[4], v[5], v[6], v[7]);
        } else {
            unsigned h[8];
            #pragma unroll
            for (int j = 0; j < 8; ++j) h[j] = f2bf(v[j]);
            uint4 o;
            o.x = h[0] | (h[1] << 16);
            o.y = h[2] | (h[3] << 16);
            o.z = h[4] | (h[5] << 16);
            o.w = h[6] | (h[7] << 16);
            *reinterpret_cast<uint4*>((unsigned short*)outv + (size_t)r * C + cg * 8) = o;
            if constexpr (STATS) {
                const float w = (float)cnt_next[r];
                #pragma unroll
                for (int j = 0; j < 8; ++j) {
                    float rv = bf2f(h[j]);
                    s[j] += w * rv;
                    q[j] += w * rv * rv;
                }
            }
        }
    }
    if constexpr (STATS) {
        #pragma unroll
        for (int j = 0; j < 8; ++j) red[lr][cg][j] = s[j];
        __syncthreads();
        if (tid < G) {
            float ss[8] = {};
            #pragma unroll
            for (int l = 0; l < NL; ++l)
                #pragma unroll
                for (int j = 0; j < 8; ++j) ss[j] += red[l][tid][j];
            #pragma unroll
            for (int j = 0; j < 8; ++j)
                part[((size_t)blockIdx.x * C + tid * 8 + j) * 2] = ss[j];
        }
        __syncthreads();
        #pragma unroll
        for (int j = 0; j < 8; ++j) red[lr][cg][j] = q[j];
        __syncthreads();
        if (tid < G) {
            float qq[8] = {};
            #pragma unroll
            for (int l = 0; l < NL; ++l)
                #pragma unroll
                for (int j = 0; j < 8; ++j) qq[j] += red[l][tid][j];
            #pragma unroll
            for (int j = 0; j < 8; ++j)
                part[((size_t)blockIdx.x * C + tid * 8 + j) * 2 + 1] = qq[j];
        }
    }
}

extern "C" void kernel_launch(void* const* d_in, const int* in_sizes, int n_in,
                              void* d_out, int out_size, void* d_ws, size_t ws_size,
                              hipStream_t stream) {
    const float* f0    = (const float*)d_in[0];
    const float* f1    = (const float*)d_in[1];
    const float* f2    = (const float*)d_in[2];
    const float* f3    = (const float*)d_in[3];
    const float* bn_w2 = (const float*)d_in[4];
    const float* bn_b2 = (const float*)d_in[5];
    const float* W2    = (const float*)d_in[6];
    const float* bn_w1 = (const float*)d_in[7];
    const float* bn_b1 = (const float*)d_in[8];
    const float* W1    = (const float*)d_in[9];
    const float* bn_w0 = (const float*)d_in[10];
    const float* bn_b0 = (const float*)d_in[11];
    const float* W0    = (const float*)d_in[12];
    const int*   idx0  = (const int*)d_in[13];
    const int*   idx1  = (const int*)d_in[14];
    const int*   idx2  = (const int*)d_in[15];
    float* out = (float*)d_out;

    // ---- workspace layout (aliased; lifetimes verified against launch order) ----
    char* wsb = (char*)d_ws;
    unsigned short* f3bf = (unsigned short*)wsb;             // [0,4MB)   dead after gemm2
    unsigned short* dec2 = (unsigned short*)(wsb + 4 * MB);  // [4,6MB)   dead after passA
    float* part2 = (float*)(wsb + 6 * MB);                   // [6,7MB)   dead after redfin2
    float* part1 = (float*)(wsb + 7 * MB);                   // [7,8MB)   dead after redfin1
    unsigned short* dec1 = (unsigned short*)(wsb + 4 * MB);  // [4,8MB)   written by gemm1 (after redfin1)
    unsigned short* dec0 = (unsigned short*)wsb;             // [0,8MB)   written by gemm0 (after passB)
    unsigned short* f2p  = (unsigned short*)(wsb + 8 * MB);  // [8,16MB)
    unsigned short* f1p  = (unsigned short*)(wsb + 16 * MB); // [16,32MB)
    unsigned short* Wp2  = (unsigned short*)(wsb + 32 * MB); // 256KB
    unsigned short* Wp1  = Wp2 + 4 * 64 * 512;               // 64KB
    unsigned short* Wp0  = Wp1 + 2 * 64 * 256;               // 16KB
    int* cnt3 = (int*)(Wp0 + 64 * 128);                      // zero region start
    int* cnt2 = cnt3 + PN3;
    int* cnt1 = cnt2 + PN2;                                  // zero region end
    float* part0 = (float*)(cnt1 + PN1);                     // 1MB
    float* scale2 = part0 + 1024 * 128 * 2;
    float* shift2 = scale2 + 512;
    float* scale1 = shift2 + 512;
    float* shift1 = scale1 + 256;
    float* scale0 = shift1 + 256;
    float* shift0 = scale0 + 128;
    float* d2 = shift0 + 128;
    float* d1 = d2 + 256;
    float* d0 = d1 + 128;

    hipMemsetAsync(cnt3, 0, (size_t)(PN3 + PN2 + PN1) * sizeof(int), stream);
    hist_all<<<dim3(PN0 / 256, 3), 256, 0, stream>>>(idx0, idx1, idx2, cnt3, cnt2, cnt1);

    // ---- level 2: dec2 = decode(f3) dense; f2p = f2 + dec2[idx0] (+stats for lvl1) ----
    stats_f3<512><<<256, 256, 0, stream>>>(f3, cnt3, part2, f3bf);
    redfin<<<512 / 32, 256, 0, stream>>>(part2, 256, 512, bn_w2, bn_b2, 1.f / PN2, scale2, shift2);
    prescale<512><<<16, 256, 0, stream>>>(W2, scale2, shift2, Wp2, d2);
    gemm_dense<512, 256, 4><<<dim3(PN3 / 64, 4), 256, 0, stream>>>(f3bf, Wp2, d2, dec2);
    gather_add<256, 4, true, false><<<PN2 / 32, 256, 0, stream>>>(f2, dec2, idx0, cnt2,
                                                                  f2p, part1);

    // ---- level 1 ----
    redfin<<<256 / 32, 256, 0, stream>>>(part1, 512, 256, bn_w1, bn_b1, 1.f / PN1, scale1, shift1);
    prescale<256><<<8, 256, 0, stream>>>(W1, scale1, shift1, Wp1, d1);
    gemm_dense<256, 128, 4><<<dim3(PN2 / 64, 2), 256, 0, stream>>>(f2p, Wp1, d1, dec1);
    gather_add<128, 4, true, false><<<PN1 / 64, 256, 0, stream>>>(f1, dec1, idx1, cnt1,
                                                                  f1p, part0);

    // ---- level 0 ----
    redfin<<<128 / 32, 256, 0, stream>>>(part0, 1024, 128, bn_w0, bn_b0, 1.f / PN0, scale0, shift0);
    prescale<128><<<4, 256, 0, stream>>>(W0, scale0, shift0, Wp0, d0);
    gemm_dense<128, 64, 4><<<dim3(PN1 / 64, 1), 256, 0, stream>>>(f1p, Wp0, d0, dec0);
    gather_add<64, 4, false, true><<<PN0 / 128, 256, 0, stream>>>(f0, dec0, idx2, nullptr,
                                                                  out, nullptr);
}